// Round 18
// baseline (127.735 us; speedup 1.0000x reference)
//
#include <hip/hip_runtime.h>
#include <hip/hip_bf16.h>

namespace {

constexpr int B_ = 8, S = 2048, D = 256, H = 4, HD = 64;
constexpr int M = B_ * S;  // 16384

typedef __attribute__((ext_vector_type(8))) short bf16x8;
typedef __attribute__((ext_vector_type(4))) short bf16x4;
typedef __attribute__((ext_vector_type(4))) float f32x4;
typedef __attribute__((ext_vector_type(16))) float f32x16;
typedef __attribute__((ext_vector_type(4))) unsigned uint4v;

__device__ inline short f2bf(float x) {
  __hip_bfloat16 h = __float2bfloat16(x);
  short s;
  __builtin_memcpy(&s, &h, 2);
  return s;
}

__device__ inline f32x4 mfma16(bf16x8 a, bf16x8 b, f32x4 c) {
  return __builtin_amdgcn_mfma_f32_16x16x32_bf16(a, b, c, 0, 0, 0);
}
__device__ inline f32x16 mfma32(bf16x8 a, bf16x8 b, f32x16 c) {
  return __builtin_amdgcn_mfma_f32_32x32x16_bf16(a, b, c, 0, 0, 0);
}

// raw 2^x
__device__ inline float exp2a(float x) {
  float r;
  asm("v_exp_f32 %0, %1" : "=v"(r) : "v"(x));
  return r;
}

// HW packed f32x2 -> bf16x2 (RNE)
__device__ inline unsigned cvtpk(float lo, float hi) {
  unsigned r;
  asm("v_cvt_pk_bf16_f32 %0, %1, %2" : "=v"(r) : "v"(lo), "v"(hi));
  return r;
}

__device__ inline bf16x4 pk4(float a, float b, float c, float d) {
  unsigned lo = cvtpk(a, b), hi = cvtpk(c, d);
  uint2 u{lo, hi};
  bf16x4 r;
  __builtin_memcpy(&r, &u, 8);
  return r;
}

// load 8 fp32, convert to bf16x8
__device__ inline bf16x8 ld_cvt8(const float* p) {
  float4 a = *(const float4*)p;
  float4 b = *(const float4*)(p + 4);
  uint4v u = {cvtpk(a.x, a.y), cvtpk(a.z, a.w), cvtpk(b.x, b.y), cvtpk(b.z, b.w)};
  bf16x8 r;
  __builtin_memcpy(&r, &u, 16);
  return r;
}

// ---------------------------------------------------------------------------
// Prep: 64 blocks transpose W{q,k,v,o} fp32[k][n] -> bf16 Wt[n][k].
// ---------------------------------------------------------------------------
__global__ __launch_bounds__(256) void prep_w_kernel(
    const float* __restrict__ Wq, const float* __restrict__ Wk,
    const float* __restrict__ Wv, const float* __restrict__ Wo,
    short* __restrict__ WqT, short* __restrict__ WkT,
    short* __restrict__ WvT, short* __restrict__ WoT) {
  const int blk = blockIdx.x, t = threadIdx.x;
  const int wq = blk >> 4, n0 = (blk & 15) * 16;
  const float* W = wq == 0 ? Wq : wq == 1 ? Wk : wq == 2 ? Wv : Wo;
  short* Wt = wq == 0 ? WqT : wq == 1 ? WkT : wq == 2 ? WvT : WoT;
#pragma unroll
  for (int j4 = 0; j4 < 4; ++j4) {
    float4 v = *(const float4*)(W + (size_t)t * 256 + n0 + j4 * 4);
    Wt[(n0 + j4 * 4 + 0) * 256 + t] = f2bf(v.x);
    Wt[(n0 + j4 * 4 + 1) * 256 + t] = f2bf(v.y);
    Wt[(n0 + j4 * 4 + 2) * 256 + t] = f2bf(v.z);
    Wt[(n0 + j4 * 4 + 3) * 256 + t] = f2bf(v.w);
  }
}

// ---------------------------------------------------------------------------
// QKV GEMM: x staged fp32 -> cvt_pk -> LDS. Q scale folds 1/8*log2e;
// V written [bh][d][s] via operand swap.
// ---------------------------------------------------------------------------
__global__ __launch_bounds__(256) void gemm_qkv_kernel(
    const float* __restrict__ x,
    const short* __restrict__ WqT, const short* __restrict__ WkT,
    const short* __restrict__ WvT,
    const float* __restrict__ bq, const float* __restrict__ bk,
    const float* __restrict__ bv,
    short* __restrict__ Qo, short* __restrict__ Ko, short* __restrict__ Vt) {
  const int bx = blockIdx.x;
  const int which = blockIdx.y;
  const short* Wt = which == 0 ? WqT : which == 1 ? WkT : WvT;
  const float* bias = which == 0 ? bq : which == 1 ? bk : bv;

  __shared__ short Xs[2][64 * 32];
  __shared__ short Ws[2][256 * 32];

  const int tid = threadIdx.x;
  const int wid = tid >> 6, lane = tid & 63;
  const int l15 = lane & 15, l4 = lane >> 4;
  const int nt0 = wid * 4;

  const float* xsrc = x + ((size_t)(bx * 64 + (tid >> 2))) * 256 + (tid & 3) * 8;
  const short* wsrc = Wt + ((size_t)(tid >> 2)) * 256 + (tid & 3) * 8;
  short* xdst0 = &Xs[0][tid * 8];
  short* xdst1 = &Xs[1][tid * 8];
  short* wdst0 = &Ws[0][tid * 8];
  short* wdst1 = &Ws[1][tid * 8];

  bf16x8 xr, wr[4];
  xr = ld_cvt8(xsrc);
#pragma unroll
  for (int p = 0; p < 4; ++p) wr[p] = *(const bf16x8*)(wsrc + (size_t)p * 64 * 256);
  *(bf16x8*)xdst0 = xr;
#pragma unroll
  for (int p = 0; p < 4; ++p) *(bf16x8*)(wdst0 + p * 2048) = wr[p];
  __syncthreads();

  f32x4 acc[4][4];
#pragma unroll
  for (int i = 0; i < 4; ++i)
#pragma unroll
    for (int mh = 0; mh < 4; ++mh) acc[i][mh] = f32x4{0.f, 0.f, 0.f, 0.f};

  for (int ks = 0; ks < 8; ++ks) {
    const int cur = ks & 1;
    if (ks < 7) {
      xr = ld_cvt8(xsrc + (ks + 1) * 32);
#pragma unroll
      for (int p = 0; p < 4; ++p)
        wr[p] = *(const bf16x8*)(wsrc + (size_t)p * 64 * 256 + (ks + 1) * 32);
    }
    bf16x8 wf[4], xf[4];
#pragma unroll
    for (int i = 0; i < 4; ++i)
      wf[i] = *(const bf16x8*)&Ws[cur][((nt0 + i) * 16 + l15) * 32 + l4 * 8];
#pragma unroll
    for (int mh = 0; mh < 4; ++mh)
      xf[mh] = *(const bf16x8*)&Xs[cur][(mh * 16 + l15) * 32 + l4 * 8];
    if (which == 2) {
#pragma unroll
      for (int i = 0; i < 4; ++i)
#pragma unroll
        for (int mh = 0; mh < 4; ++mh)
          acc[i][mh] = mfma16(xf[mh], wf[i], acc[i][mh]);  // D[m][n]
    } else {
#pragma unroll
      for (int i = 0; i < 4; ++i)
#pragma unroll
        for (int mh = 0; mh < 4; ++mh)
          acc[i][mh] = mfma16(wf[i], xf[mh], acc[i][mh]);  // D[n][m]
    }
    if (ks < 7) {
      short* xd = (cur ? xdst0 : xdst1);
      short* wd = (cur ? wdst0 : wdst1);
      *(bf16x8*)xd = xr;
#pragma unroll
      for (int p = 0; p < 4; ++p) *(bf16x8*)(wd + p * 2048) = wr[p];
    }
    __syncthreads();
  }

  if (which == 2) {
    const int m0 = bx * 64 + l4 * 4;
#pragma unroll
    for (int i = 0; i < 4; ++i) {
      const int n = (nt0 + i) * 16 + l15;
      const float bi = bias[n];
      const int h = n >> 6, d = n & 63;
#pragma unroll
      for (int mh = 0; mh < 4; ++mh) {
        const int m = m0 + mh * 16;
        const int bb = m >> 11, s0 = m & 2047;
        bf16x4 r = pk4(acc[i][mh][0] + bi, acc[i][mh][1] + bi,
                       acc[i][mh][2] + bi, acc[i][mh][3] + bi);
        *(bf16x4*)(Vt + (((size_t)bb * H + h) * HD + d) * S + s0) = r;
      }
    }
  } else {
    const float scale = which == 0 ? 0.18033688011112042f : 1.0f;  // 1/8*log2e
    short* outp = which == 0 ? Qo : Ko;
#pragma unroll
    for (int i = 0; i < 4; ++i) {
      const int n0 = (nt0 + i) * 16 + l4 * 4;
      float4 bi = *(const float4*)(bias + n0);
      const int h = n0 >> 6, d0 = n0 & 63;
#pragma unroll
      for (int mh = 0; mh < 4; ++mh) {
        const int m = bx * 64 + mh * 16 + l15;
        const int bb = m >> 11, s = m & 2047;
        bf16x4 r = pk4((acc[i][mh][0] + bi.x) * scale, (acc[i][mh][1] + bi.y) * scale,
                       (acc[i][mh][2] + bi.z) * scale, (acc[i][mh][3] + bi.w) * scale);
        *(bf16x4*)(outp + (((size_t)bb * H + h) * S + s) * HD + d0) = r;
      }
    }
  }
}

// ---------------------------------------------------------------------------
// Out projection GEMM (bf16 A in, fp32 out)
// ---------------------------------------------------------------------------
__global__ __launch_bounds__(256) void gemm_out_kernel(
    const short* __restrict__ Abf, const short* __restrict__ WoT,
    const float* __restrict__ bo, float* __restrict__ out) {
  const int bx = blockIdx.x;
  __shared__ short Xs[2][64 * 32];
  __shared__ short Ws[2][256 * 32];

  const int tid = threadIdx.x;
  const int wid = tid >> 6, lane = tid & 63;
  const int l15 = lane & 15, l4 = lane >> 4;
  const int nt0 = wid * 4;

  const short* xsrc = Abf + ((size_t)(bx * 64 + (tid >> 2))) * 256 + (tid & 3) * 8;
  const short* wsrc = WoT + ((size_t)(tid >> 2)) * 256 + (tid & 3) * 8;
  short* xdst0 = &Xs[0][tid * 8];
  short* xdst1 = &Xs[1][tid * 8];
  short* wdst0 = &Ws[0][tid * 8];
  short* wdst1 = &Ws[1][tid * 8];

  bf16x8 xr, wr[4];
  xr = *(const bf16x8*)xsrc;
#pragma unroll
  for (int p = 0; p < 4; ++p) wr[p] = *(const bf16x8*)(wsrc + (size_t)p * 64 * 256);
  *(bf16x8*)xdst0 = xr;
#pragma unroll
  for (int p = 0; p < 4; ++p) *(bf16x8*)(wdst0 + p * 2048) = wr[p];
  __syncthreads();

  f32x4 acc[4][4];
#pragma unroll
  for (int i = 0; i < 4; ++i)
#pragma unroll
    for (int mh = 0; mh < 4; ++mh) acc[i][mh] = f32x4{0.f, 0.f, 0.f, 0.f};

  for (int ks = 0; ks < 8; ++ks) {
    const int cur = ks & 1;
    if (ks < 7) {
      xr = *(const bf16x8*)(xsrc + (ks + 1) * 32);
#pragma unroll
      for (int p = 0; p < 4; ++p)
        wr[p] = *(const bf16x8*)(wsrc + (size_t)p * 64 * 256 + (ks + 1) * 32);
    }
    bf16x8 wf[4], xf[4];
#pragma unroll
    for (int i = 0; i < 4; ++i)
      wf[i] = *(const bf16x8*)&Ws[cur][((nt0 + i) * 16 + l15) * 32 + l4 * 8];
#pragma unroll
    for (int mh = 0; mh < 4; ++mh)
      xf[mh] = *(const bf16x8*)&Xs[cur][(mh * 16 + l15) * 32 + l4 * 8];
#pragma unroll
    for (int i = 0; i < 4; ++i)
#pragma unroll
      for (int mh = 0; mh < 4; ++mh)
        acc[i][mh] = mfma16(wf[i], xf[mh], acc[i][mh]);
    if (ks < 7) {
      short* xd = (cur ? xdst0 : xdst1);
      short* wd = (cur ? wdst0 : wdst1);
      *(bf16x8*)xd = xr;
#pragma unroll
      for (int p = 0; p < 4; ++p) *(bf16x8*)(wd + p * 2048) = wr[p];
    }
    __syncthreads();
  }

#pragma unroll
  for (int i = 0; i < 4; ++i) {
    const int n0 = (nt0 + i) * 16 + l4 * 4;
    float4 bi = *(const float4*)(bo + n0);
#pragma unroll
    for (int mh = 0; mh < 4; ++mh) {
      const int m = bx * 64 + mh * 16 + l15;
      float4 r;
      r.x = acc[i][mh][0] + bi.x;
      r.y = acc[i][mh][1] + bi.y;
      r.z = acc[i][mh][2] + bi.z;
      r.w = acc[i][mh][3] + bi.w;
      *(float4*)(out + (size_t)m * 256 + n0) = r;
    }
  }
}

// ---------------------------------------------------------------------------
// Flash attention v16: K DIRECT FROM L2 (no K LDS!) with register ping-pong
// prefetch (kfA/kfB = 8 x bf16x8 fragments, loaded one tile ahead). All 4
// waves of a block previously read IDENTICAL K fragments from LDS -- that
// 4x-redundant traffic moves to L2 (L2-resident: 512KB/bh, bh->XCD fixed).
// V stays in packed LDS (8KB tiles, triple-buffered, lag-2 reads), single
// barrier (V-only hazards). lsum moved from ones-MFMA to VALU adds in
// EXPPACK + final shfl_xor(32) (R6-verified). PV deferred by 2 (R17),
// exp deferred by 1 (R16). LDS 24KB/block.
// ---------------------------------------------------------------------------
__global__ __launch_bounds__(256) void attn_kernel16(
    const short* __restrict__ Q, const short* __restrict__ K,
    const short* __restrict__ VT, short* __restrict__ Abf) {
  const int lin = blockIdx.x;   // 512
  const int bh = lin & 31;      // same-bh blocks land on same XCD
  const int qt = lin >> 5;      // 0..15
  const int tid = threadIdx.x, wid = tid >> 6, lane = tid & 63;
  const int q31 = lane & 31, h = lane >> 5;
  constexpr int NT = S / 64;  // 32

  __shared__ short Vs[3][32 * 128];  // packed [64][64] V^T tiles, 8KB each

  const short* Kg = K + (size_t)bh * S * HD;
  const short* Vg = VT + (size_t)bh * HD * S;
  const int qrow = qt * 128 + wid * 32;

  const short* Qg = Q + ((size_t)bh * S + qrow + q31) * HD + h * 8;
  bf16x8 qf[4];
#pragma unroll
  for (int ds = 0; ds < 4; ++ds) qf[ds] = *(const bf16x8*)(Qg + ds * 16);

  // V staging (packed layout, same as R13/R17)
  const int srow = tid >> 2;
  const int pr = srow & 31;
  const int scol = (tid & 3) * 16;
  const int cb0 = ((srow >> 5) << 6) + scol;
  const int swz = (pr & 15) * 8;
  const int c0 = cb0 ^ swz;
  const int c1 = (cb0 + 8) ^ swz;
  const int sbase = pr * 128;

  // V fragment read cols
  const int fs = (q31 & 15) * 8;
  int colA[4], colB[4];
#pragma unroll
  for (int ds = 0; ds < 4; ++ds) {
    colA[ds] = (ds * 16 + h * 8) ^ fs;
    colB[ds] = (64 + ds * 16 + h * 8) ^ fs;
  }
  const int rbase = q31 * 128;

  // K fragment base (direct global): lane (q31,h) reads K[kv=q31][ds*16+h*8]
  const short* kfp = Kg + (size_t)q31 * HD + h * 8;

  f32x16 o0, o1, scA0, scA1, scB0, scB1;
#pragma unroll
  for (int i = 0; i < 16; ++i) { o0[i] = 0.f; o1[i] = 0.f; }
  bf16x8 pBA[4], pBB[4], kfA[8], kfB[8];
  bf16x8 vr0, vr1;
  float lacc = 0.f;

#define LOADKF(KT, KF)                                                \
  {                                                                   \
    const short* kp_ = kfp + (size_t)(KT) * 64 * HD;                  \
    _Pragma("unroll") for (int ds = 0; ds < 4; ++ds) {                \
      KF[ds] = *(const bf16x8*)(kp_ + ds * 16);                       \
      KF[4 + ds] = *(const bf16x8*)(kp_ + 32 * HD + ds * 16);         \
    }                                                                 \
  }

#define LOADV(KT)                                                          \
  {                                                                        \
    vr0 = *(const bf16x8*)(Vg + (size_t)srow * S + (KT) * 64 + scol);      \
    vr1 = *(const bf16x8*)(Vg + (size_t)srow * S + (KT) * 64 + scol + 8);  \
  }

#define STAGEV()                                                      \
  {                                                                   \
    short* vw_ = &Vs[vw][0];                                          \
    *(bf16x8*)&vw_[sbase + c0] = vr0;                                 \
    *(bf16x8*)&vw_[sbase + c1] = vr1;                                 \
  }

#define QKBURST(KF, SCN0, SCN1)                                       \
  {                                                                   \
    _Pragma("unroll") for (int i = 0; i < 16; ++i) {                  \
      SCN0[i] = 0.f;                                                  \
      SCN1[i] = 0.f;                                                  \
    }                                                                 \
    _Pragma("unroll") for (int ds = 0; ds < 4; ++ds) {                \
      SCN0 = mfma32(KF[ds], qf[ds], SCN0);                            \
      SCN1 = mfma32(KF[4 + ds], qf[ds], SCN1);                        \
    }                                                                 \
  }

#define PVBURST(VB, PB)                                               \
  {                                                                   \
    const short* vb_ = (VB);                                          \
    _Pragma("unroll") for (int ds = 0; ds < 4; ++ds) {                \
      bf16x8 v0 = *(const bf16x8*)&vb_[rbase + colA[ds]];             \
      bf16x8 v1 = *(const bf16x8*)&vb_[rbase + colB[ds]];             \
      o0 = mfma32(v0, PB[ds], o0);                                    \
      o1 = mfma32(v1, PB[ds], o1);                                    \
    }                                                                 \
  }

  // exp + pack + VALU lsum
#define EXPPACK(S0, S1, PB)                                           \
  {                                                                   \
    _Pragma("unroll") for (int win = 0; win < 2; ++win) {             \
      const f32x16& sc = win ? (S1) : (S0);                           \
      float p[16];                                                    \
      float a0 = 0.f, a1 = 0.f, a2 = 0.f, a3 = 0.f;                   \
      _Pragma("unroll") for (int r = 0; r < 16; r += 4) {             \
        p[r + 0] = exp2a(sc[r + 0]);                                  \
        p[r + 1] = exp2a(sc[r + 1]);                                  \
        p[r + 2] = exp2a(sc[r + 2]);                                  \
        p[r + 3] = exp2a(sc[r + 3]);                                  \
        a0 += p[r + 0]; a1 += p[r + 1];                               \
        a2 += p[r + 2]; a3 += p[r + 3];                               \
      }                                                               \
      lacc += (a0 + a1) + (a2 + a3);                                  \
      unsigned w[8];                                                  \
      _Pragma("unroll") for (int i = 0; i < 8; ++i)                   \
          w[i] = cvtpk(p[2 * i], p[2 * i + 1]);                       \
      unsigned x0 = w[0], y0 = w[2], x1 = w[1], y1 = w[3];            \
      unsigned x2 = w[4], y2 = w[6], x3 = w[5], y3 = w[7];            \
      asm("v_permlane32_swap_b32 %0, %1" : "+v"(x0), "+v"(y0));       \
      asm("v_permlane32_swap_b32 %0, %1" : "+v"(x1), "+v"(y1));       \
      asm("v_permlane32_swap_b32 %0, %1" : "+v"(x2), "+v"(y2));       \
      asm("v_permlane32_swap_b32 %0, %1" : "+v"(x3), "+v"(y3));       \
      uint4v u0 = {x0, x1, y0, y1};                                   \
      uint4v u1 = {x2, x3, y2, y3};                                   \
      __builtin_memcpy(&PB[win * 2 + 0], &u0, 16);                    \
      __builtin_memcpy(&PB[win * 2 + 1], &u1, 16);                    \
    }                                                                 \
  }

  int vw = 0;  // V write slot = t % 3

  // ---- prologue: kfA = Kfrag(0); vr = V(0) ----
  LOADKF(0, kfA);
  LOADV(0);

  // ---- peel t=0: QK(0)->scA; kfB = Kfrag(1); stage V(0); barrier ----
  {
    __builtin_amdgcn_s_setprio(1);
    QKBURST(kfA, scA0, scA1);
    __builtin_amdgcn_s_setprio(0);
    LOADKF(1, kfB);
    STAGEV();
    __syncthreads();
    vw = 1;
  }

  // ---- peel t=1: V(1); QK(1)->scB || EXPPACK(scA)->pBA; kfA=Kfrag(2);
  //      stage V(1); barrier ----
  {
    LOADV(1);
    __builtin_amdgcn_s_setprio(1);
    QKBURST(kfB, scB0, scB1);
    __builtin_amdgcn_s_setprio(0);
    EXPPACK(scA0, scA1, pBA);
    LOADKF(2, kfA);
    STAGEV();
    __syncthreads();
    vw = 2;
  }

  // STEP(t): V(t) load; {QK(t) from KFC || PV(t-2) w/ PBO}; EXPPACK(SCP)->PBN;
  //          KFN = Kfrag(t+1); stage V(t); barrier.
#define STEP(KT, KFC, KFN, SCN0, SCN1, SCP0, SCP1, PBN, PBO)          \
  {                                                                   \
    LOADV(KT);                                                        \
    const int vr2 = (vw + 1 == 3) ? 0 : vw + 1; /* (t-2)%3 */         \
    __builtin_amdgcn_s_setprio(1);                                    \
    QKBURST(KFC, SCN0, SCN1);                                         \
    PVBURST(&Vs[vr2][0], PBO);                                        \
    __builtin_amdgcn_s_setprio(0);                                    \
    EXPPACK(SCP0, SCP1, PBN);                                         \
    if ((KT) + 1 < NT) LOADKF((KT) + 1, KFN);                         \
    STAGEV();                                                         \
    __syncthreads();                                                  \
    vw = (vw == 2) ? 0 : vw + 1;                                      \
  }

  // ---- main loop: t = 2..NT-1 (even/odd pairs; NT-2 = 30 even) ----
  for (int kt = 2; kt < NT; kt += 2) {
    STEP(kt, kfA, kfB, scA0, scA1, scB0, scB1, pBB, pBA);      // even t
    STEP(kt + 1, kfB, kfA, scB0, scB1, scA0, scA1, pBA, pBB);  // odd t
  }

  // ---- epilogue ----
  // after loop: scB=sc(31), pBA=exp(sc(30)); PV done through 29.
  // vw = 32%3 = 2. V(30) slot = 0; V(31) slot = 1.
  {
    __builtin_amdgcn_s_setprio(1);
    PVBURST(&Vs[0][0], pBA);  // PV(30)
    __builtin_amdgcn_s_setprio(0);
    EXPPACK(scB0, scB1, pBB);
    __builtin_amdgcn_s_setprio(1);
    PVBURST(&Vs[1][0], pBB);  // PV(31)
    __builtin_amdgcn_s_setprio(0);
  }
#undef STEP
#undef EXPPACK
#undef PVBURST
#undef QKBURST
#undef STAGEV
#undef LOADV
#undef LOADKF

  // l for this lane's q column: partner lane (l^32) holds the other halves
  const float lall = lacc + __shfl_xor(lacc, 32);
  const float inv = 1.0f / lall;
  const int b = bh >> 2, hh = bh & 3;
  short* ap = Abf + ((size_t)b * S + qrow + q31) * 256 + hh * 64;
#pragma unroll
  for (int dt = 0; dt < 2; ++dt) {
    const f32x16& o = dt ? o1 : o0;
#pragma unroll
    for (int g = 0; g < 4; ++g) {
      const int d0 = dt * 32 + 8 * g + 4 * h;
      bf16x4 r = pk4(o[4 * g + 0] * inv, o[4 * g + 1] * inv,
                     o[4 * g + 2] * inv, o[4 * g + 3] * inv);
      *(bf16x4*)(ap + d0) = r;
    }
  }
}

}  // namespace

extern "C" void kernel_launch(void* const* d_in, const int* in_sizes, int n_in,
                              void* d_out, int out_size, void* d_ws, size_t ws_size,
                              hipStream_t stream) {
  const float* x  = (const float*)d_in[0];
  const float* Wq = (const float*)d_in[1];
  const float* bq = (const float*)d_in[2];
  const float* Wk = (const float*)d_in[3];
  const float* bk = (const float*)d_in[4];
  const float* Wv = (const float*)d_in[5];
  const float* bv = (const float*)d_in[6];
  const float* Wo = (const float*)d_in[7];
  const float* bo = (const float*)d_in[8];
  float* out = (float*)d_out;

  const size_t per = (size_t)M * D;
  short* WqT = (short*)d_ws;
  short* WkT = WqT + 256 * 256;
  short* WvT = WkT + 256 * 256;
  short* WoT = WvT + 256 * 256;
  short* Qbf = WoT + 256 * 256;
  short* Kbf = Qbf + per;
  short* Vt  = Kbf + per;          // [bh][d][s]
  short* Abf = Vt + per;

  prep_w_kernel<<<64, 256, 0, stream>>>(Wq, Wk, Wv, Wo, WqT, WkT, WvT, WoT);
  gemm_qkv_kernel<<<dim3(256, 3), 256, 0, stream>>>(x, WqT, WkT, WvT, bq, bk, bv,
                                                    Qbf, Kbf, Vt);
  attn_kernel16<<<512, 256, 0, stream>>>(Qbf, Kbf, Vt, Abf);
  gemm_out_kernel<<<256, 256, 0, stream>>>(Abf, WoT, bo, out);
}

// Round 19
// 96.518 us; speedup vs baseline: 1.3234x; 1.3234x over previous
//
#include <hip/hip_runtime.h>
#include <hip/hip_bf16.h>

namespace {

constexpr int B_ = 8, S = 2048, D = 256, H = 4, HD = 64;
constexpr int M = B_ * S;  // 16384

typedef __attribute__((ext_vector_type(8))) short bf16x8;
typedef __attribute__((ext_vector_type(4))) short bf16x4;
typedef __attribute__((ext_vector_type(4))) float f32x4;
typedef __attribute__((ext_vector_type(16))) float f32x16;
typedef __attribute__((ext_vector_type(4))) unsigned uint4v;

__device__ inline short f2bf(float x) {
  __hip_bfloat16 h = __float2bfloat16(x);
  short s;
  __builtin_memcpy(&s, &h, 2);
  return s;
}

__device__ inline f32x4 mfma16(bf16x8 a, bf16x8 b, f32x4 c) {
  return __builtin_amdgcn_mfma_f32_16x16x32_bf16(a, b, c, 0, 0, 0);
}
__device__ inline f32x16 mfma32(bf16x8 a, bf16x8 b, f32x16 c) {
  return __builtin_amdgcn_mfma_f32_32x32x16_bf16(a, b, c, 0, 0, 0);
}

// raw 2^x
__device__ inline float exp2a(float x) {
  float r;
  asm("v_exp_f32 %0, %1" : "=v"(r) : "v"(x));
  return r;
}

// HW packed f32x2 -> bf16x2 (RNE)
__device__ inline unsigned cvtpk(float lo, float hi) {
  unsigned r;
  asm("v_cvt_pk_bf16_f32 %0, %1, %2" : "=v"(r) : "v"(lo), "v"(hi));
  return r;
}

__device__ inline bf16x4 pk4(float a, float b, float c, float d) {
  unsigned lo = cvtpk(a, b), hi = cvtpk(c, d);
  uint2 u{lo, hi};
  bf16x4 r;
  __builtin_memcpy(&r, &u, 8);
  return r;
}

// load 8 fp32, convert to bf16x8
__device__ inline bf16x8 ld_cvt8(const float* p) {
  float4 a = *(const float4*)p;
  float4 b = *(const float4*)(p + 4);
  uint4v u = {cvtpk(a.x, a.y), cvtpk(a.z, a.w), cvtpk(b.x, b.y), cvtpk(b.z, b.w)};
  bf16x8 r;
  __builtin_memcpy(&r, &u, 16);
  return r;
}

// ---------------------------------------------------------------------------
// Prep: 64 blocks transpose W{q,k,v,o} fp32[k][n] -> bf16 Wt[n][k].
// ---------------------------------------------------------------------------
__global__ __launch_bounds__(256) void prep_w_kernel(
    const float* __restrict__ Wq, const float* __restrict__ Wk,
    const float* __restrict__ Wv, const float* __restrict__ Wo,
    short* __restrict__ WqT, short* __restrict__ WkT,
    short* __restrict__ WvT, short* __restrict__ WoT) {
  const int blk = blockIdx.x, t = threadIdx.x;
  const int wq = blk >> 4, n0 = (blk & 15) * 16;
  const float* W = wq == 0 ? Wq : wq == 1 ? Wk : wq == 2 ? Wv : Wo;
  short* Wt = wq == 0 ? WqT : wq == 1 ? WkT : wq == 2 ? WvT : WoT;
#pragma unroll
  for (int j4 = 0; j4 < 4; ++j4) {
    float4 v = *(const float4*)(W + (size_t)t * 256 + n0 + j4 * 4);
    Wt[(n0 + j4 * 4 + 0) * 256 + t] = f2bf(v.x);
    Wt[(n0 + j4 * 4 + 1) * 256 + t] = f2bf(v.y);
    Wt[(n0 + j4 * 4 + 2) * 256 + t] = f2bf(v.z);
    Wt[(n0 + j4 * 4 + 3) * 256 + t] = f2bf(v.w);
  }
}

// ---------------------------------------------------------------------------
// FUSED QKV GEMM: one pass over x computes Q, K, V (logical N = 768).
// 512 blocks x 32 m-rows. All three W^T slabs share ONE 48KB LDS buffer
// (single-buffered, 2 barriers/ks, 12-reg prefetch); Xs double-buffered.
// Wave w owns n-tiles w*12..w*12+11 (16 tiles per matrix; tiles don't
// straddle matrices... tile 16n boundaries align with 256 splits).
// Q scale folds 1/8*log2e; V written [bh][d][s] via its D[n][m]=[d][s]
// orientation. x is read from HBM exactly once.
// ---------------------------------------------------------------------------
__global__ __launch_bounds__(256) void gemm_qkv_fused(
    const float* __restrict__ x,
    const short* __restrict__ WqT, const short* __restrict__ WkT,
    const short* __restrict__ WvT,
    const float* __restrict__ bq, const float* __restrict__ bk,
    const float* __restrict__ bv,
    short* __restrict__ Qo, short* __restrict__ Ko, short* __restrict__ Vt) {
  const int bx = blockIdx.x;  // 0..511
  const int tid = threadIdx.x;
  const int wid = tid >> 6, lane = tid & 63;
  const int l15 = lane & 15, l4 = lane >> 4;

  __shared__ short Xs[2][32 * 32];   // [m][k] bf16, 2KB each
  __shared__ short Wall[768 * 32];   // [n][k] bf16, 48KB

  // W staging map: unit g = j*256+tid covers n = g>>2, kc = (g&3)*8
  const short* wsrc[12];
#pragma unroll
  for (int j = 0; j < 12; ++j) {
    const int g = j * 256 + tid;
    const int n = g >> 2;
    const int kc = (g & 3) * 8;
    const short* Wp = (n < 256) ? WqT : (n < 512) ? WkT : WvT;
    wsrc[j] = Wp + (size_t)(n & 255) * 256 + kc;
  }

  const float* xsrc = x + ((size_t)(bx * 32 + (tid >> 2))) * 256 + (tid & 3) * 8;
  const int xoff = (tid >> 2) * 32 + (tid & 3) * 8;

  // ---- stage ks = 0 ----
  bf16x8 wr[12];
#pragma unroll
  for (int j = 0; j < 12; ++j) wr[j] = *(const bf16x8*)(wsrc[j]);
  bf16x8 xr;
  if (tid < 128) xr = ld_cvt8(xsrc);
#pragma unroll
  for (int j = 0; j < 12; ++j)
    *(bf16x8*)&Wall[(j * 256 + tid) * 8] = wr[j];
  if (tid < 128) *(bf16x8*)&Xs[0][xoff] = xr;
  __syncthreads();

  f32x4 acc[12][2];
#pragma unroll
  for (int i = 0; i < 12; ++i) {
    acc[i][0] = f32x4{0.f, 0.f, 0.f, 0.f};
    acc[i][1] = f32x4{0.f, 0.f, 0.f, 0.f};
  }

  for (int ks = 0; ks < 8; ++ks) {
    const int cur = ks & 1;
    if (ks < 7) {  // prefetch next chunk into regs (lands during compute)
#pragma unroll
      for (int j = 0; j < 12; ++j)
        wr[j] = *(const bf16x8*)(wsrc[j] + (ks + 1) * 32);
      if (tid < 128) xr = ld_cvt8(xsrc + (ks + 1) * 32);
    }
    bf16x8 xfA = *(const bf16x8*)&Xs[cur][(l15)*32 + l4 * 8];
    bf16x8 xfB = *(const bf16x8*)&Xs[cur][(16 + l15) * 32 + l4 * 8];
#pragma unroll
    for (int i = 0; i < 12; ++i) {
      bf16x8 wf = *(const bf16x8*)&Wall[((wid * 12 + i) * 16 + l15) * 32 + l4 * 8];
      acc[i][0] = mfma16(wf, xfA, acc[i][0]);  // D[n][m]
      acc[i][1] = mfma16(wf, xfB, acc[i][1]);
    }
    if (ks < 7) {
      __syncthreads();  // all compute on Wall done
#pragma unroll
      for (int j = 0; j < 12; ++j)
        *(bf16x8*)&Wall[(j * 256 + tid) * 8] = wr[j];
      if (tid < 128) *(bf16x8*)&Xs[cur ^ 1][xoff] = xr;
      __syncthreads();  // staged chunk visible
    }
  }

  // ---- epilogue ----
  const float qscale = 0.18033688011112042f;  // 1/8 * log2(e)
#pragma unroll
  for (int i = 0; i < 12; ++i) {
    const int n_tile = wid * 12 + i;          // 0..47
    const int which = n_tile >> 4;            // 0=Q 1=K 2=V (wave-uniform)
    const int nbase = (n_tile & 15) * 16 + l4 * 4;  // 0..252 within matrix
    const int h = nbase >> 6;
    if (which == 2) {
      float4 bi = *(const float4*)(bv + nbase);
      const float bi4[4] = {bi.x, bi.y, bi.z, bi.w};
#pragma unroll
      for (int mh = 0; mh < 2; ++mh) {
        const int m = bx * 32 + mh * 16 + l15;
        const int bb = m >> 11, s = m & 2047;
#pragma unroll
        for (int r = 0; r < 4; ++r) {
          const int d = (nbase + r) & 63;
          Vt[(((size_t)bb * H + h) * HD + d) * S + s] =
              f2bf(acc[i][mh][r] + bi4[r]);
        }
      }
    } else {
      const float* bias = (which == 0) ? bq : bk;
      const float scale = (which == 0) ? qscale : 1.0f;
      short* outp = (which == 0) ? Qo : Ko;
      float4 bi = *(const float4*)(bias + nbase);
      const int d0 = nbase & 63;
#pragma unroll
      for (int mh = 0; mh < 2; ++mh) {
        const int m = bx * 32 + mh * 16 + l15;
        const int bb = m >> 11, s = m & 2047;
        bf16x4 r = pk4((acc[i][mh][0] + bi.x) * scale,
                       (acc[i][mh][1] + bi.y) * scale,
                       (acc[i][mh][2] + bi.z) * scale,
                       (acc[i][mh][3] + bi.w) * scale);
        *(bf16x4*)(outp + (((size_t)bb * H + h) * S + s) * HD + d0) = r;
      }
    }
  }
}

// ---------------------------------------------------------------------------
// Out projection GEMM (bf16 A in, fp32 out)
// ---------------------------------------------------------------------------
__global__ __launch_bounds__(256) void gemm_out_kernel(
    const short* __restrict__ Abf, const short* __restrict__ WoT,
    const float* __restrict__ bo, float* __restrict__ out) {
  const int bx = blockIdx.x;
  __shared__ short Xs[2][64 * 32];
  __shared__ short Ws[2][256 * 32];

  const int tid = threadIdx.x;
  const int wid = tid >> 6, lane = tid & 63;
  const int l15 = lane & 15, l4 = lane >> 4;
  const int nt0 = wid * 4;

  const short* xsrc = Abf + ((size_t)(bx * 64 + (tid >> 2))) * 256 + (tid & 3) * 8;
  const short* wsrc = WoT + ((size_t)(tid >> 2)) * 256 + (tid & 3) * 8;
  short* xdst0 = &Xs[0][tid * 8];
  short* xdst1 = &Xs[1][tid * 8];
  short* wdst0 = &Ws[0][tid * 8];
  short* wdst1 = &Ws[1][tid * 8];

  bf16x8 xr, wr[4];
  xr = *(const bf16x8*)xsrc;
#pragma unroll
  for (int p = 0; p < 4; ++p) wr[p] = *(const bf16x8*)(wsrc + (size_t)p * 64 * 256);
  *(bf16x8*)xdst0 = xr;
#pragma unroll
  for (int p = 0; p < 4; ++p) *(bf16x8*)(wdst0 + p * 2048) = wr[p];
  __syncthreads();

  f32x4 acc[4][4];
#pragma unroll
  for (int i = 0; i < 4; ++i)
#pragma unroll
    for (int mh = 0; mh < 4; ++mh) acc[i][mh] = f32x4{0.f, 0.f, 0.f, 0.f};

  for (int ks = 0; ks < 8; ++ks) {
    const int cur = ks & 1;
    if (ks < 7) {
      xr = *(const bf16x8*)(xsrc + (ks + 1) * 32);
#pragma unroll
      for (int p = 0; p < 4; ++p)
        wr[p] = *(const bf16x8*)(wsrc + (size_t)p * 64 * 256 + (ks + 1) * 32);
    }
    bf16x8 wf[4], xf[4];
#pragma unroll
    for (int i = 0; i < 4; ++i)
      wf[i] = *(const bf16x8*)&Ws[cur][((nt0 + i) * 16 + l15) * 32 + l4 * 8];
#pragma unroll
    for (int mh = 0; mh < 4; ++mh)
      xf[mh] = *(const bf16x8*)&Xs[cur][(mh * 16 + l15) * 32 + l4 * 8];
#pragma unroll
    for (int i = 0; i < 4; ++i)
#pragma unroll
      for (int mh = 0; mh < 4; ++mh)
        acc[i][mh] = mfma16(wf[i], xf[mh], acc[i][mh]);
    if (ks < 7) {
      short* xd = (cur ? xdst0 : xdst1);
      short* wd = (cur ? wdst0 : wdst1);
      *(bf16x8*)xd = xr;
#pragma unroll
      for (int p = 0; p < 4; ++p) *(bf16x8*)(wd + p * 2048) = wr[p];
    }
    __syncthreads();
  }

#pragma unroll
  for (int i = 0; i < 4; ++i) {
    const int n0 = (nt0 + i) * 16 + l4 * 4;
    float4 bi = *(const float4*)(bo + n0);
#pragma unroll
    for (int mh = 0; mh < 4; ++mh) {
      const int m = bx * 64 + mh * 16 + l15;
      float4 r;
      r.x = acc[i][mh][0] + bi.x;
      r.y = acc[i][mh][1] + bi.y;
      r.z = acc[i][mh][2] + bi.z;
      r.w = acc[i][mh][3] + bi.w;
      *(float4*)(out + (size_t)m * 256 + n0) = r;
    }
  }
}

// ---------------------------------------------------------------------------
// Flash attention v15 (R17, proven 47.5us): PV deferred by 2, exp deferred
// by 1, packed 8KB tiles, K dbuf + V tri-buf, single barrier per tile.
// ---------------------------------------------------------------------------
__global__ __launch_bounds__(256) void attn_kernel15(
    const short* __restrict__ Q, const short* __restrict__ K,
    const short* __restrict__ VT, short* __restrict__ Abf) {
  const int lin = blockIdx.x;   // 512
  const int bh = lin & 31;      // same-bh blocks land on same XCD
  const int qt = lin >> 5;      // 0..15
  const int tid = threadIdx.x, wid = tid >> 6, lane = tid & 63;
  const int q31 = lane & 31, h = lane >> 5;
  constexpr int NT = S / 64;  // 32

  __shared__ short Ks[2][32 * 128];  // packed [64][64] tiles, 8KB each
  __shared__ short Vs[3][32 * 128];

  const short* Kg = K + (size_t)bh * S * HD;
  const short* Vg = VT + (size_t)bh * HD * S;
  const int qrow = qt * 128 + wid * 32;

  const short* Qg = Q + ((size_t)bh * S + qrow + q31) * HD + h * 8;
  bf16x8 qf[4];
#pragma unroll
  for (int ds = 0; ds < 4; ++ds) qf[ds] = *(const bf16x8*)(Qg + ds * 16);

  bf16x8 ones;
#pragma unroll
  for (int i = 0; i < 8; ++i) ones[i] = (short)0x3F80;

  const int srow = tid >> 2;
  const int pr = srow & 31;
  const int scol = (tid & 3) * 16;
  const int cb0 = ((srow >> 5) << 6) + scol;
  const int swz = (pr & 15) * 8;
  const int c0 = cb0 ^ swz;
  const int c1 = (cb0 + 8) ^ swz;
  const int sbase = pr * 128;

  const int fs = (q31 & 15) * 8;
  int colA[4], colB[4];
#pragma unroll
  for (int ds = 0; ds < 4; ++ds) {
    colA[ds] = (ds * 16 + h * 8) ^ fs;
    colB[ds] = (64 + ds * 16 + h * 8) ^ fs;
  }
  const int rbase = q31 * 128;

  bf16x8 kr0, kr1, vr0, vr1;
  kr0 = *(const bf16x8*)(Kg + (size_t)srow * HD + scol);
  kr1 = *(const bf16x8*)(Kg + (size_t)srow * HD + scol + 8);
  *(bf16x8*)&Ks[0][sbase + c0] = kr0;
  *(bf16x8*)&Ks[0][sbase + c1] = kr1;
  {
    const short* Kn = Kg + (size_t)64 * HD;
    kr0 = *(const bf16x8*)(Kn + (size_t)srow * HD + scol);
    kr1 = *(const bf16x8*)(Kn + (size_t)srow * HD + scol + 8);
    vr0 = *(const bf16x8*)(Vg + (size_t)srow * S + scol);
    vr1 = *(const bf16x8*)(Vg + (size_t)srow * S + scol + 8);
  }
  __syncthreads();

  f32x16 o0, o1, lsum, scA0, scA1, scB0, scB1;
#pragma unroll
  for (int i = 0; i < 16; ++i) { o0[i] = 0.f; o1[i] = 0.f; lsum[i] = 0.f; }
  bf16x8 pBA[4], pBB[4];

#define EXPPACK(S0, S1, PB)                                           \
  {                                                                   \
    _Pragma("unroll") for (int win = 0; win < 2; ++win) {             \
      const f32x16& sc = win ? (S1) : (S0);                           \
      float p[16];                                                    \
      _Pragma("unroll") for (int r = 0; r < 16; ++r)                  \
          p[r] = exp2a(sc[r]);                                        \
      unsigned w[8];                                                  \
      _Pragma("unroll") for (int i = 0; i < 8; ++i)                   \
          w[i] = cvtpk(p[2 * i], p[2 * i + 1]);                       \
      unsigned x0 = w[0], y0 = w[2], x1 = w[1], y1 = w[3];            \
      unsigned x2 = w[4], y2 = w[6], x3 = w[5], y3 = w[7];            \
      asm("v_permlane32_swap_b32 %0, %1" : "+v"(x0), "+v"(y0));       \
      asm("v_permlane32_swap_b32 %0, %1" : "+v"(x1), "+v"(y1));       \
      asm("v_permlane32_swap_b32 %0, %1" : "+v"(x2), "+v"(y2));       \
      asm("v_permlane32_swap_b32 %0, %1" : "+v"(x3), "+v"(y3));       \
      uint4v u0 = {x0, x1, y0, y1};                                   \
      uint4v u1 = {x2, x3, y2, y3};                                   \
      __builtin_memcpy(&PB[win * 2 + 0], &u0, 16);                    \
      __builtin_memcpy(&PB[win * 2 + 1], &u1, 16);                    \
    }                                                                 \
  }

#define QKBURST(KB, SCN0, SCN1)                                       \
  {                                                                   \
    _Pragma("unroll") for (int i = 0; i < 16; ++i) {                  \
      SCN0[i] = 0.f;                                                  \
      SCN1[i] = 0.f;                                                  \
    }                                                                 \
    const short* kb_ = (KB);                                          \
    _Pragma("unroll") for (int ds = 0; ds < 4; ++ds) {                \
      bf16x8 k0 = *(const bf16x8*)&kb_[rbase + colA[ds]];             \
      bf16x8 k1 = *(const bf16x8*)&kb_[rbase + colB[ds]];             \
      SCN0 = mfma32(k0, qf[ds], SCN0);                                \
      SCN1 = mfma32(k1, qf[ds], SCN1);                                \
    }                                                                 \
  }

#define PVBURST(VB, PB)                                               \
  {                                                                   \
    const short* vb_ = (VB);                                          \
    _Pragma("unroll") for (int ds = 0; ds < 4; ++ds) {                \
      bf16x8 v0 = *(const bf16x8*)&vb_[rbase + colA[ds]];             \
      bf16x8 v1 = *(const bf16x8*)&vb_[rbase + colB[ds]];             \
      o0 = mfma32(v0, PB[ds], o0);                                    \
      o1 = mfma32(v1, PB[ds], o1);                                    \
      lsum = mfma32(ones, PB[ds], lsum);                              \
    }                                                                 \
  }

#define STAGEWR(KT)                                                   \
  {                                                                   \
    if ((KT) + 1 < NT) {                                              \
      short* kw = &Ks[((KT) + 1) & 1][0];                             \
      *(bf16x8*)&kw[sbase + c0] = kr0;                                \
      *(bf16x8*)&kw[sbase + c1] = kr1;                                \
    }                                                                 \
    short* vw_ = &Vs[vw][0];                                          \
    *(bf16x8*)&vw_[sbase + c0] = vr0;                                 \
    *(bf16x8*)&vw_[sbase + c1] = vr1;                                 \
  }

#define LOADS(KT)                                                          \
  {                                                                        \
    if ((KT) + 1 < NT) {                                                   \
      const short* Kn = Kg + (size_t)((KT) + 1) * 64 * HD;                 \
      kr0 = *(const bf16x8*)(Kn + (size_t)srow * HD + scol);               \
      kr1 = *(const bf16x8*)(Kn + (size_t)srow * HD + scol + 8);           \
    }                                                                      \
    vr0 = *(const bf16x8*)(Vg + (size_t)srow * S + (KT) * 64 + scol);      \
    vr1 = *(const bf16x8*)(Vg + (size_t)srow * S + (KT) * 64 + scol + 8);  \
  }

  int vw = 0;

  {
    __builtin_amdgcn_s_setprio(1);
    QKBURST(&Ks[0][0], scA0, scA1);
    __builtin_amdgcn_s_setprio(0);
    STAGEWR(0);
    __syncthreads();
    vw = 1;
  }

  {
    LOADS(1);
    __builtin_amdgcn_s_setprio(1);
    QKBURST(&Ks[1][0], scB0, scB1);
    __builtin_amdgcn_s_setprio(0);
    EXPPACK(scA0, scA1, pBA);
    STAGEWR(1);
    __syncthreads();
    vw = 2;
  }

#define STEP(KT, SCN0, SCN1, SCP0, SCP1, PBN, PBO)                    \
  {                                                                   \
    LOADS(KT);                                                        \
    const int vr2 = (vw + 1 == 3) ? 0 : vw + 1; /* (t-2)%3 */         \
    __builtin_amdgcn_s_setprio(1);                                    \
    QKBURST(&Ks[(KT)&1][0], SCN0, SCN1);                              \
    PVBURST(&Vs[vr2][0], PBO);                                        \
    __builtin_amdgcn_s_setprio(0);                                    \
    EXPPACK(SCP0, SCP1, PBN);                                         \
    STAGEWR(KT);                                                      \
    __syncthreads();                                                  \
    vw = (vw == 2) ? 0 : vw + 1;                                      \
  }

  for (int kt = 2; kt < NT; kt += 2) {
    STEP(kt, scA0, scA1, scB0, scB1, pBB, pBA);
    STEP(kt + 1, scB0, scB1, scA0, scA1, pBA, pBB);
  }

  {
    __builtin_amdgcn_s_setprio(1);
    PVBURST(&Vs[0][0], pBA);  // PV(30)
    __builtin_amdgcn_s_setprio(0);
    EXPPACK(scB0, scB1, pBB);
    __builtin_amdgcn_s_setprio(1);
    PVBURST(&Vs[1][0], pBB);  // PV(31)
    __builtin_amdgcn_s_setprio(0);
  }
#undef STEP
#undef LOADS
#undef STAGEWR
#undef PVBURST
#undef QKBURST
#undef EXPPACK

  const float inv = 1.0f / lsum[0];
  const int b = bh >> 2, hh = bh & 3;
  short* ap = Abf + ((size_t)b * S + qrow + q31) * 256 + hh * 64;
#pragma unroll
  for (int dt = 0; dt < 2; ++dt) {
    const f32x16& o = dt ? o1 : o0;
#pragma unroll
    for (int g = 0; g < 4; ++g) {
      const int d0 = dt * 32 + 8 * g + 4 * h;
      bf16x4 r = pk4(o[4 * g + 0] * inv, o[4 * g + 1] * inv,
                     o[4 * g + 2] * inv, o[4 * g + 3] * inv);
      *(bf16x4*)(ap + d0) = r;
    }
  }
}

}  // namespace

extern "C" void kernel_launch(void* const* d_in, const int* in_sizes, int n_in,
                              void* d_out, int out_size, void* d_ws, size_t ws_size,
                              hipStream_t stream) {
  const float* x  = (const float*)d_in[0];
  const float* Wq = (const float*)d_in[1];
  const float* bq = (const float*)d_in[2];
  const float* Wk = (const float*)d_in[3];
  const float* bk = (const float*)d_in[4];
  const float* Wv = (const float*)d_in[5];
  const float* bv = (const float*)d_in[6];
  const float* Wo = (const float*)d_in[7];
  const float* bo = (const float*)d_in[8];
  float* out = (float*)d_out;

  const size_t per = (size_t)M * D;
  short* WqT = (short*)d_ws;
  short* WkT = WqT + 256 * 256;
  short* WvT = WkT + 256 * 256;
  short* WoT = WvT + 256 * 256;
  short* Qbf = WoT + 256 * 256;
  short* Kbf = Qbf + per;
  short* Vt  = Kbf + per;          // [bh][d][s]
  short* Abf = Vt + per;

  prep_w_kernel<<<64, 256, 0, stream>>>(Wq, Wk, Wv, Wo, WqT, WkT, WvT, WoT);
  gemm_qkv_fused<<<512, 256, 0, stream>>>(x, WqT, WkT, WvT, bq, bk, bv,
                                          Qbf, Kbf, Vt);
  attn_kernel15<<<512, 256, 0, stream>>>(Qbf, Kbf, Vt, Abf);
  gemm_out_kernel<<<256, 256, 0, stream>>>(Abf, WoT, bo, out);
}

// Round 20
// 83.010 us; speedup vs baseline: 1.5388x; 1.1627x over previous
//
#include <hip/hip_runtime.h>
#include <hip/hip_bf16.h>

namespace {

constexpr int B_ = 8, S = 2048, D = 256, H = 4, HD = 64;
constexpr int M = B_ * S;  // 16384

typedef __attribute__((ext_vector_type(8))) short bf16x8;
typedef __attribute__((ext_vector_type(4))) short bf16x4;
typedef __attribute__((ext_vector_type(4))) float f32x4;
typedef __attribute__((ext_vector_type(16))) float f32x16;
typedef __attribute__((ext_vector_type(4))) unsigned uint4v;

__device__ inline short f2bf(float x) {
  __hip_bfloat16 h = __float2bfloat16(x);
  short s;
  __builtin_memcpy(&s, &h, 2);
  return s;
}

__device__ inline f32x4 mfma16(bf16x8 a, bf16x8 b, f32x4 c) {
  return __builtin_amdgcn_mfma_f32_16x16x32_bf16(a, b, c, 0, 0, 0);
}
__device__ inline f32x16 mfma32(bf16x8 a, bf16x8 b, f32x16 c) {
  return __builtin_amdgcn_mfma_f32_32x32x16_bf16(a, b, c, 0, 0, 0);
}

// raw 2^x
__device__ inline float exp2a(float x) {
  float r;
  asm("v_exp_f32 %0, %1" : "=v"(r) : "v"(x));
  return r;
}

// HW packed f32x2 -> bf16x2 (RNE)
__device__ inline unsigned cvtpk(float lo, float hi) {
  unsigned r;
  asm("v_cvt_pk_bf16_f32 %0, %1, %2" : "=v"(r) : "v"(lo), "v"(hi));
  return r;
}

__device__ inline bf16x4 pk4(float a, float b, float c, float d) {
  unsigned lo = cvtpk(a, b), hi = cvtpk(c, d);
  uint2 u{lo, hi};
  bf16x4 r;
  __builtin_memcpy(&r, &u, 8);
  return r;
}

// load 8 fp32, convert to bf16x8
__device__ inline bf16x8 ld_cvt8(const float* p) {
  float4 a = *(const float4*)p;
  float4 b = *(const float4*)(p + 4);
  uint4v u = {cvtpk(a.x, a.y), cvtpk(a.z, a.w), cvtpk(b.x, b.y), cvtpk(b.z, b.w)};
  bf16x8 r;
  __builtin_memcpy(&r, &u, 16);
  return r;
}

// ---------------------------------------------------------------------------
// Prep: 64 blocks transpose W{q,k,v,o} fp32[k][n] -> bf16 Wt[n][k].
// ---------------------------------------------------------------------------
__global__ __launch_bounds__(256) void prep_w_kernel(
    const float* __restrict__ Wq, const float* __restrict__ Wk,
    const float* __restrict__ Wv, const float* __restrict__ Wo,
    short* __restrict__ WqT, short* __restrict__ WkT,
    short* __restrict__ WvT, short* __restrict__ WoT) {
  const int blk = blockIdx.x, t = threadIdx.x;
  const int wq = blk >> 4, n0 = (blk & 15) * 16;
  const float* W = wq == 0 ? Wq : wq == 1 ? Wk : wq == 2 ? Wv : Wo;
  short* Wt = wq == 0 ? WqT : wq == 1 ? WkT : wq == 2 ? WvT : WoT;
#pragma unroll
  for (int j4 = 0; j4 < 4; ++j4) {
    float4 v = *(const float4*)(W + (size_t)t * 256 + n0 + j4 * 4);
    Wt[(n0 + j4 * 4 + 0) * 256 + t] = f2bf(v.x);
    Wt[(n0 + j4 * 4 + 1) * 256 + t] = f2bf(v.y);
    Wt[(n0 + j4 * 4 + 2) * 256 + t] = f2bf(v.z);
    Wt[(n0 + j4 * 4 + 3) * 256 + t] = f2bf(v.w);
  }
}

// ---------------------------------------------------------------------------
// QKV GEMM: x staged fp32 -> cvt_pk -> LDS. Q scale folds 1/8*log2e;
// V written [bh][d][s] via operand swap.
// ---------------------------------------------------------------------------
__global__ __launch_bounds__(256) void gemm_qkv_kernel(
    const float* __restrict__ x,
    const short* __restrict__ WqT, const short* __restrict__ WkT,
    const short* __restrict__ WvT,
    const float* __restrict__ bq, const float* __restrict__ bk,
    const float* __restrict__ bv,
    short* __restrict__ Qo, short* __restrict__ Ko, short* __restrict__ Vt) {
  const int bx = blockIdx.x;
  const int which = blockIdx.y;
  const short* Wt = which == 0 ? WqT : which == 1 ? WkT : WvT;
  const float* bias = which == 0 ? bq : which == 1 ? bk : bv;

  __shared__ short Xs[2][64 * 32];
  __shared__ short Ws[2][256 * 32];

  const int tid = threadIdx.x;
  const int wid = tid >> 6, lane = tid & 63;
  const int l15 = lane & 15, l4 = lane >> 4;
  const int nt0 = wid * 4;

  const float* xsrc = x + ((size_t)(bx * 64 + (tid >> 2))) * 256 + (tid & 3) * 8;
  const short* wsrc = Wt + ((size_t)(tid >> 2)) * 256 + (tid & 3) * 8;
  short* xdst0 = &Xs[0][tid * 8];
  short* xdst1 = &Xs[1][tid * 8];
  short* wdst0 = &Ws[0][tid * 8];
  short* wdst1 = &Ws[1][tid * 8];

  bf16x8 xr, wr[4];
  xr = ld_cvt8(xsrc);
#pragma unroll
  for (int p = 0; p < 4; ++p) wr[p] = *(const bf16x8*)(wsrc + (size_t)p * 64 * 256);
  *(bf16x8*)xdst0 = xr;
#pragma unroll
  for (int p = 0; p < 4; ++p) *(bf16x8*)(wdst0 + p * 2048) = wr[p];
  __syncthreads();

  f32x4 acc[4][4];
#pragma unroll
  for (int i = 0; i < 4; ++i)
#pragma unroll
    for (int mh = 0; mh < 4; ++mh) acc[i][mh] = f32x4{0.f, 0.f, 0.f, 0.f};

  for (int ks = 0; ks < 8; ++ks) {
    const int cur = ks & 1;
    if (ks < 7) {
      xr = ld_cvt8(xsrc + (ks + 1) * 32);
#pragma unroll
      for (int p = 0; p < 4; ++p)
        wr[p] = *(const bf16x8*)(wsrc + (size_t)p * 64 * 256 + (ks + 1) * 32);
    }
    bf16x8 wf[4], xf[4];
#pragma unroll
    for (int i = 0; i < 4; ++i)
      wf[i] = *(const bf16x8*)&Ws[cur][((nt0 + i) * 16 + l15) * 32 + l4 * 8];
#pragma unroll
    for (int mh = 0; mh < 4; ++mh)
      xf[mh] = *(const bf16x8*)&Xs[cur][(mh * 16 + l15) * 32 + l4 * 8];
    if (which == 2) {
#pragma unroll
      for (int i = 0; i < 4; ++i)
#pragma unroll
        for (int mh = 0; mh < 4; ++mh)
          acc[i][mh] = mfma16(xf[mh], wf[i], acc[i][mh]);  // D[m][n]
    } else {
#pragma unroll
      for (int i = 0; i < 4; ++i)
#pragma unroll
        for (int mh = 0; mh < 4; ++mh)
          acc[i][mh] = mfma16(wf[i], xf[mh], acc[i][mh]);  // D[n][m]
    }
    if (ks < 7) {
      short* xd = (cur ? xdst0 : xdst1);
      short* wd = (cur ? wdst0 : wdst1);
      *(bf16x8*)xd = xr;
#pragma unroll
      for (int p = 0; p < 4; ++p) *(bf16x8*)(wd + p * 2048) = wr[p];
    }
    __syncthreads();
  }

  if (which == 2) {
    const int m0 = bx * 64 + l4 * 4;
#pragma unroll
    for (int i = 0; i < 4; ++i) {
      const int n = (nt0 + i) * 16 + l15;
      const float bi = bias[n];
      const int h = n >> 6, d = n & 63;
#pragma unroll
      for (int mh = 0; mh < 4; ++mh) {
        const int m = m0 + mh * 16;
        const int bb = m >> 11, s0 = m & 2047;
        bf16x4 r = pk4(acc[i][mh][0] + bi, acc[i][mh][1] + bi,
                       acc[i][mh][2] + bi, acc[i][mh][3] + bi);
        *(bf16x4*)(Vt + (((size_t)bb * H + h) * HD + d) * S + s0) = r;
      }
    }
  } else {
    const float scale = which == 0 ? 0.18033688011112042f : 1.0f;  // 1/8*log2e
    short* outp = which == 0 ? Qo : Ko;
#pragma unroll
    for (int i = 0; i < 4; ++i) {
      const int n0 = (nt0 + i) * 16 + l4 * 4;
      float4 bi = *(const float4*)(bias + n0);
      const int h = n0 >> 6, d0 = n0 & 63;
#pragma unroll
      for (int mh = 0; mh < 4; ++mh) {
        const int m = bx * 64 + mh * 16 + l15;
        const int bb = m >> 11, s = m & 2047;
        bf16x4 r = pk4((acc[i][mh][0] + bi.x) * scale, (acc[i][mh][1] + bi.y) * scale,
                       (acc[i][mh][2] + bi.z) * scale, (acc[i][mh][3] + bi.w) * scale);
        *(bf16x4*)(outp + (((size_t)bb * H + h) * S + s) * HD + d0) = r;
      }
    }
  }
}

// ---------------------------------------------------------------------------
// Out projection GEMM (bf16 A in, fp32 out)
// ---------------------------------------------------------------------------
__global__ __launch_bounds__(256) void gemm_out_kernel(
    const short* __restrict__ Abf, const short* __restrict__ WoT,
    const float* __restrict__ bo, float* __restrict__ out) {
  const int bx = blockIdx.x;
  __shared__ short Xs[2][64 * 32];
  __shared__ short Ws[2][256 * 32];

  const int tid = threadIdx.x;
  const int wid = tid >> 6, lane = tid & 63;
  const int l15 = lane & 15, l4 = lane >> 4;
  const int nt0 = wid * 4;

  const short* xsrc = Abf + ((size_t)(bx * 64 + (tid >> 2))) * 256 + (tid & 3) * 8;
  const short* wsrc = WoT + ((size_t)(tid >> 2)) * 256 + (tid & 3) * 8;
  short* xdst0 = &Xs[0][tid * 8];
  short* xdst1 = &Xs[1][tid * 8];
  short* wdst0 = &Ws[0][tid * 8];
  short* wdst1 = &Ws[1][tid * 8];

  bf16x8 xr, wr[4];
  xr = *(const bf16x8*)xsrc;
#pragma unroll
  for (int p = 0; p < 4; ++p) wr[p] = *(const bf16x8*)(wsrc + (size_t)p * 64 * 256);
  *(bf16x8*)xdst0 = xr;
#pragma unroll
  for (int p = 0; p < 4; ++p) *(bf16x8*)(wdst0 + p * 2048) = wr[p];
  __syncthreads();

  f32x4 acc[4][4];
#pragma unroll
  for (int i = 0; i < 4; ++i)
#pragma unroll
    for (int mh = 0; mh < 4; ++mh) acc[i][mh] = f32x4{0.f, 0.f, 0.f, 0.f};

  for (int ks = 0; ks < 8; ++ks) {
    const int cur = ks & 1;
    if (ks < 7) {
      xr = *(const bf16x8*)(xsrc + (ks + 1) * 32);
#pragma unroll
      for (int p = 0; p < 4; ++p)
        wr[p] = *(const bf16x8*)(wsrc + (size_t)p * 64 * 256 + (ks + 1) * 32);
    }
    bf16x8 wf[4], xf[4];
#pragma unroll
    for (int i = 0; i < 4; ++i)
      wf[i] = *(const bf16x8*)&Ws[cur][((nt0 + i) * 16 + l15) * 32 + l4 * 8];
#pragma unroll
    for (int mh = 0; mh < 4; ++mh)
      xf[mh] = *(const bf16x8*)&Xs[cur][(mh * 16 + l15) * 32 + l4 * 8];
#pragma unroll
    for (int i = 0; i < 4; ++i)
#pragma unroll
      for (int mh = 0; mh < 4; ++mh)
        acc[i][mh] = mfma16(wf[i], xf[mh], acc[i][mh]);
    if (ks < 7) {
      short* xd = (cur ? xdst0 : xdst1);
      short* wd = (cur ? wdst0 : wdst1);
      *(bf16x8*)xd = xr;
#pragma unroll
      for (int p = 0; p < 4; ++p) *(bf16x8*)(wd + p * 2048) = wr[p];
    }
    __syncthreads();
  }

#pragma unroll
  for (int i = 0; i < 4; ++i) {
    const int n0 = (nt0 + i) * 16 + l4 * 4;
    float4 bi = *(const float4*)(bo + n0);
#pragma unroll
    for (int mh = 0; mh < 4; ++mh) {
      const int m = bx * 64 + mh * 16 + l15;
      float4 r;
      r.x = acc[i][mh][0] + bi.x;
      r.y = acc[i][mh][1] + bi.y;
      r.z = acc[i][mh][2] + bi.z;
      r.w = acc[i][mh][3] + bi.w;
      *(float4*)(out + (size_t)m * 256 + n0) = r;
    }
  }
}

// ---------------------------------------------------------------------------
// Flash attention v15 (R17, proven 47.5us): PV deferred by 2, exp deferred
// by 1, packed 8KB tiles, K dbuf + V tri-buf, single barrier per tile.
// ---------------------------------------------------------------------------
__global__ __launch_bounds__(256) void attn_kernel15(
    const short* __restrict__ Q, const short* __restrict__ K,
    const short* __restrict__ VT, short* __restrict__ Abf) {
  const int lin = blockIdx.x;   // 512
  const int bh = lin & 31;      // same-bh blocks land on same XCD
  const int qt = lin >> 5;      // 0..15
  const int tid = threadIdx.x, wid = tid >> 6, lane = tid & 63;
  const int q31 = lane & 31, h = lane >> 5;
  constexpr int NT = S / 64;  // 32

  __shared__ short Ks[2][32 * 128];  // packed [64][64] tiles, 8KB each
  __shared__ short Vs[3][32 * 128];

  const short* Kg = K + (size_t)bh * S * HD;
  const short* Vg = VT + (size_t)bh * HD * S;
  const int qrow = qt * 128 + wid * 32;

  const short* Qg = Q + ((size_t)bh * S + qrow + q31) * HD + h * 8;
  bf16x8 qf[4];
#pragma unroll
  for (int ds = 0; ds < 4; ++ds) qf[ds] = *(const bf16x8*)(Qg + ds * 16);

  bf16x8 ones;
#pragma unroll
  for (int i = 0; i < 8; ++i) ones[i] = (short)0x3F80;

  const int srow = tid >> 2;
  const int pr = srow & 31;
  const int scol = (tid & 3) * 16;
  const int cb0 = ((srow >> 5) << 6) + scol;
  const int swz = (pr & 15) * 8;
  const int c0 = cb0 ^ swz;
  const int c1 = (cb0 + 8) ^ swz;
  const int sbase = pr * 128;

  const int fs = (q31 & 15) * 8;
  int colA[4], colB[4];
#pragma unroll
  for (int ds = 0; ds < 4; ++ds) {
    colA[ds] = (ds * 16 + h * 8) ^ fs;
    colB[ds] = (64 + ds * 16 + h * 8) ^ fs;
  }
  const int rbase = q31 * 128;

  bf16x8 kr0, kr1, vr0, vr1;
  kr0 = *(const bf16x8*)(Kg + (size_t)srow * HD + scol);
  kr1 = *(const bf16x8*)(Kg + (size_t)srow * HD + scol + 8);
  *(bf16x8*)&Ks[0][sbase + c0] = kr0;
  *(bf16x8*)&Ks[0][sbase + c1] = kr1;
  {
    const short* Kn = Kg + (size_t)64 * HD;
    kr0 = *(const bf16x8*)(Kn + (size_t)srow * HD + scol);
    kr1 = *(const bf16x8*)(Kn + (size_t)srow * HD + scol + 8);
    vr0 = *(const bf16x8*)(Vg + (size_t)srow * S + scol);
    vr1 = *(const bf16x8*)(Vg + (size_t)srow * S + scol + 8);
  }
  __syncthreads();

  f32x16 o0, o1, lsum, scA0, scA1, scB0, scB1;
#pragma unroll
  for (int i = 0; i < 16; ++i) { o0[i] = 0.f; o1[i] = 0.f; lsum[i] = 0.f; }
  bf16x8 pBA[4], pBB[4];

#define EXPPACK(S0, S1, PB)                                           \
  {                                                                   \
    _Pragma("unroll") for (int win = 0; win < 2; ++win) {             \
      const f32x16& sc = win ? (S1) : (S0);                           \
      float p[16];                                                    \
      _Pragma("unroll") for (int r = 0; r < 16; ++r)                  \
          p[r] = exp2a(sc[r]);                                        \
      unsigned w[8];                                                  \
      _Pragma("unroll") for (int i = 0; i < 8; ++i)                   \
          w[i] = cvtpk(p[2 * i], p[2 * i + 1]);                       \
      unsigned x0 = w[0], y0 = w[2], x1 = w[1], y1 = w[3];            \
      unsigned x2 = w[4], y2 = w[6], x3 = w[5], y3 = w[7];            \
      asm("v_permlane32_swap_b32 %0, %1" : "+v"(x0), "+v"(y0));       \
      asm("v_permlane32_swap_b32 %0, %1" : "+v"(x1), "+v"(y1));       \
      asm("v_permlane32_swap_b32 %0, %1" : "+v"(x2), "+v"(y2));       \
      asm("v_permlane32_swap_b32 %0, %1" : "+v"(x3), "+v"(y3));       \
      uint4v u0 = {x0, x1, y0, y1};                                   \
      uint4v u1 = {x2, x3, y2, y3};                                   \
      __builtin_memcpy(&PB[win * 2 + 0], &u0, 16);                    \
      __builtin_memcpy(&PB[win * 2 + 1], &u1, 16);                    \
    }                                                                 \
  }

#define QKBURST(KB, SCN0, SCN1)                                       \
  {                                                                   \
    _Pragma("unroll") for (int i = 0; i < 16; ++i) {                  \
      SCN0[i] = 0.f;                                                  \
      SCN1[i] = 0.f;                                                  \
    }                                                                 \
    const short* kb_ = (KB);                                          \
    _Pragma("unroll") for (int ds = 0; ds < 4; ++ds) {                \
      bf16x8 k0 = *(const bf16x8*)&kb_[rbase + colA[ds]];             \
      bf16x8 k1 = *(const bf16x8*)&kb_[rbase + colB[ds]];             \
      SCN0 = mfma32(k0, qf[ds], SCN0);                                \
      SCN1 = mfma32(k1, qf[ds], SCN1);                                \
    }                                                                 \
  }

#define PVBURST(VB, PB)                                               \
  {                                                                   \
    const short* vb_ = (VB);                                          \
    _Pragma("unroll") for (int ds = 0; ds < 4; ++ds) {                \
      bf16x8 v0 = *(const bf16x8*)&vb_[rbase + colA[ds]];             \
      bf16x8 v1 = *(const bf16x8*)&vb_[rbase + colB[ds]];             \
      o0 = mfma32(v0, PB[ds], o0);                                    \
      o1 = mfma32(v1, PB[ds], o1);                                    \
      lsum = mfma32(ones, PB[ds], lsum);                              \
    }                                                                 \
  }

#define STAGEWR(KT)                                                   \
  {                                                                   \
    if ((KT) + 1 < NT) {                                              \
      short* kw = &Ks[((KT) + 1) & 1][0];                             \
      *(bf16x8*)&kw[sbase + c0] = kr0;                                \
      *(bf16x8*)&kw[sbase + c1] = kr1;                                \
    }                                                                 \
    short* vw_ = &Vs[vw][0];                                          \
    *(bf16x8*)&vw_[sbase + c0] = vr0;                                 \
    *(bf16x8*)&vw_[sbase + c1] = vr1;                                 \
  }

#define LOADS(KT)                                                          \
  {                                                                        \
    if ((KT) + 1 < NT) {                                                   \
      const short* Kn = Kg + (size_t)((KT) + 1) * 64 * HD;                 \
      kr0 = *(const bf16x8*)(Kn + (size_t)srow * HD + scol);               \
      kr1 = *(const bf16x8*)(Kn + (size_t)srow * HD + scol + 8);           \
    }                                                                      \
    vr0 = *(const bf16x8*)(Vg + (size_t)srow * S + (KT) * 64 + scol);      \
    vr1 = *(const bf16x8*)(Vg + (size_t)srow * S + (KT) * 64 + scol + 8);  \
  }

  int vw = 0;

  {
    __builtin_amdgcn_s_setprio(1);
    QKBURST(&Ks[0][0], scA0, scA1);
    __builtin_amdgcn_s_setprio(0);
    STAGEWR(0);
    __syncthreads();
    vw = 1;
  }

  {
    LOADS(1);
    __builtin_amdgcn_s_setprio(1);
    QKBURST(&Ks[1][0], scB0, scB1);
    __builtin_amdgcn_s_setprio(0);
    EXPPACK(scA0, scA1, pBA);
    STAGEWR(1);
    __syncthreads();
    vw = 2;
  }

#define STEP(KT, SCN0, SCN1, SCP0, SCP1, PBN, PBO)                    \
  {                                                                   \
    LOADS(KT);                                                        \
    const int vr2 = (vw + 1 == 3) ? 0 : vw + 1; /* (t-2)%3 */         \
    __builtin_amdgcn_s_setprio(1);                                    \
    QKBURST(&Ks[(KT)&1][0], SCN0, SCN1);                              \
    PVBURST(&Vs[vr2][0], PBO);                                        \
    __builtin_amdgcn_s_setprio(0);                                    \
    EXPPACK(SCP0, SCP1, PBN);                                         \
    STAGEWR(KT);                                                      \
    __syncthreads();                                                  \
    vw = (vw == 2) ? 0 : vw + 1;                                      \
  }

  for (int kt = 2; kt < NT; kt += 2) {
    STEP(kt, scA0, scA1, scB0, scB1, pBB, pBA);
    STEP(kt + 1, scB0, scB1, scA0, scA1, pBA, pBB);
  }

  {
    __builtin_amdgcn_s_setprio(1);
    PVBURST(&Vs[0][0], pBA);  // PV(30)
    __builtin_amdgcn_s_setprio(0);
    EXPPACK(scB0, scB1, pBB);
    __builtin_amdgcn_s_setprio(1);
    PVBURST(&Vs[1][0], pBB);  // PV(31)
    __builtin_amdgcn_s_setprio(0);
  }
#undef STEP
#undef LOADS
#undef STAGEWR
#undef PVBURST
#undef QKBURST
#undef EXPPACK

  const float inv = 1.0f / lsum[0];
  const int b = bh >> 2, hh = bh & 3;
  short* ap = Abf + ((size_t)b * S + qrow + q31) * 256 + hh * 64;
#pragma unroll
  for (int dt = 0; dt < 2; ++dt) {
    const f32x16& o = dt ? o1 : o0;
#pragma unroll
    for (int g = 0; g < 4; ++g) {
      const int d0 = dt * 32 + 8 * g + 4 * h;
      bf16x4 r = pk4(o[4 * g + 0] * inv, o[4 * g + 1] * inv,
                     o[4 * g + 2] * inv, o[4 * g + 3] * inv);
      *(bf16x4*)(ap + d0) = r;
    }
  }
}

}  // namespace

extern "C" void kernel_launch(void* const* d_in, const int* in_sizes, int n_in,
                              void* d_out, int out_size, void* d_ws, size_t ws_size,
                              hipStream_t stream) {
  const float* x  = (const float*)d_in[0];
  const float* Wq = (const float*)d_in[1];
  const float* bq = (const float*)d_in[2];
  const float* Wk = (const float*)d_in[3];
  const float* bk = (const float*)d_in[4];
  const float* Wv = (const float*)d_in[5];
  const float* bv = (const float*)d_in[6];
  const float* Wo = (const float*)d_in[7];
  const float* bo = (const float*)d_in[8];
  float* out = (float*)d_out;

  const size_t per = (size_t)M * D;
  short* WqT = (short*)d_ws;
  short* WkT = WqT + 256 * 256;
  short* WvT = WkT + 256 * 256;
  short* WoT = WvT + 256 * 256;
  short* Qbf = WoT + 256 * 256;
  short* Kbf = Qbf + per;
  short* Vt  = Kbf + per;          // [bh][d][s]
  short* Abf = Vt + per;

  prep_w_kernel<<<64, 256, 0, stream>>>(Wq, Wk, Wv, Wo, WqT, WkT, WvT, WoT);
  gemm_qkv_kernel<<<dim3(256, 3), 256, 0, stream>>>(x, WqT, WkT, WvT, bq, bk, bv,
                                                    Qbf, Kbf, Vt);
  attn_kernel15<<<512, 256, 0, stream>>>(Qbf, Kbf, Vt, Abf);
  gemm_out_kernel<<<256, 256, 0, stream>>>(Abf, WoT, bo, out);
}